// Round 1
// baseline (2721.105 us; speedup 1.0000x reference)
//
#include <hip/hip_runtime.h>

#define N_ATOMS 100000
#define N_PAIRS 3200000
#define N_PROP 16
#define N_BASIS 10
#define W 16

// tanh(x) = 1 - 2/(exp2(2*log2(e)*x) + 1); abs err ~1e-7, monotone, saturates correctly
__device__ __forceinline__ float fast_tanh(float x) {
    float e = __builtin_amdgcn_exp2f(x * 2.88539008177792681f);
    return 1.0f - 2.0f * __builtin_amdgcn_rcpf(e + 1.0f);
}

// ---------------- pp_pre: p1_in = tanh(tanh(p1@W0+b0)@W1+b1), one thread per atom
__global__ __launch_bounds__(256) void k_pp_pre(
    const float* __restrict__ p1,
    const float* __restrict__ W0, const float* __restrict__ b0,
    const float* __restrict__ W1, const float* __restrict__ b1,
    float* __restrict__ p1_in)
{
    int a = blockIdx.x * 256 + threadIdx.x;
    if (a >= N_ATOMS) return;
    const float4* src = reinterpret_cast<const float4*>(p1 + (size_t)a * N_PROP);
    float4 v0 = src[0], v1 = src[1], v2 = src[2], v3 = src[3];
    float x[N_PROP] = {v0.x,v0.y,v0.z,v0.w, v1.x,v1.y,v1.z,v1.w,
                       v2.x,v2.y,v2.z,v2.w, v3.x,v3.y,v3.z,v3.w};
    float h[W];
#pragma unroll
    for (int c = 0; c < W; ++c) h[c] = b0[c];
#pragma unroll
    for (int k = 0; k < N_PROP; ++k)
#pragma unroll
        for (int c = 0; c < W; ++c) h[c] += x[k] * W0[k*W + c];   // W0 uniform -> s_load
#pragma unroll
    for (int c = 0; c < W; ++c) h[c] = fast_tanh(h[c]);
    float y[W];
#pragma unroll
    for (int c = 0; c < W; ++c) y[c] = b1[c];
#pragma unroll
    for (int k = 0; k < W; ++k)
#pragma unroll
        for (int c = 0; c < W; ++c) y[c] += h[k] * W1[k*W + c];
    float4* dst = reinterpret_cast<float4*>(p1_in + (size_t)a * W);
    dst[0] = make_float4(fast_tanh(y[0]),  fast_tanh(y[1]),  fast_tanh(y[2]),  fast_tanh(y[3]));
    dst[1] = make_float4(fast_tanh(y[4]),  fast_tanh(y[5]),  fast_tanh(y[6]),  fast_tanh(y[7]));
    dst[2] = make_float4(fast_tanh(y[8]),  fast_tanh(y[9]),  fast_tanh(y[10]), fast_tanh(y[11]));
    dst[3] = make_float4(fast_tanh(y[12]), fast_tanh(y[13]), fast_tanh(y[14]), fast_tanh(y[15]));
}

// ---------------- pair kernel: one thread per pair
__global__ __launch_bounds__(256) void k_pair(
    const int*   __restrict__ ind2,
    const float* __restrict__ basis,
    const float* __restrict__ p1_in,
    const float* __restrict__ Wpi0, const float* __restrict__ bpi0,
    const float* __restrict__ Wpi1, const float* __restrict__ bpi1,
    const float* __restrict__ Wii0, const float* __restrict__ Wii1,
    float* __restrict__ i_pair_out, float* __restrict__ p_sum)
{
    __shared__ float vbuf[256 * W];   // per-thread 16-float scratch; stride 64B -> 2-way bank alias (free)
    int p = blockIdx.x * 256 + threadIdx.x;
    if (p >= N_PAIRS) return;
    int2 ij = reinterpret_cast<const int2*>(ind2)[p];
    int i = ij.x, j = ij.y;

    const float4* ai = reinterpret_cast<const float4*>(p1_in + (size_t)i * W);
    const float4* aj = reinterpret_cast<const float4*>(p1_in + (size_t)j * W);
    float4 A0 = ai[0], A1 = ai[1], A2 = ai[2], A3 = ai[3];
    float4 B0 = aj[0], B1 = aj[1], B2 = aj[2], B3 = aj[3];
    float in[2*W] = {A0.x,A0.y,A0.z,A0.w, A1.x,A1.y,A1.z,A1.w,
                     A2.x,A2.y,A2.z,A2.w, A3.x,A3.y,A3.z,A3.w,
                     B0.x,B0.y,B0.z,B0.w, B1.x,B1.y,B1.z,B1.w,
                     B2.x,B2.y,B2.z,B2.w, B3.x,B3.y,B3.z,B3.w};

    float bas[N_BASIS];
    const float2* bp = reinterpret_cast<const float2*>(basis + (size_t)p * N_BASIS);
#pragma unroll
    for (int b = 0; b < 5; ++b) { float2 t = bp[b]; bas[2*b] = t.x; bas[2*b+1] = t.y; }

    // pi layer 0: (2W)->W, bias, tanh
    float h0[W];
#pragma unroll
    for (int c = 0; c < W; ++c) h0[c] = bpi0[c];
#pragma unroll
    for (int k = 0; k < 2*W; ++k)
#pragma unroll
        for (int c = 0; c < W; ++c) h0[c] += in[k] * Wpi0[k*W + c];
#pragma unroll
    for (int c = 0; c < W; ++c) h0[c] = fast_tanh(h0[c]);

    // pi layer 1: W -> W*N_BASIS, bias, tanh, then contract with basis
    for (int c = 0; c < W; ++c) {          // runtime loop (code-size control)
        float acc[N_BASIS];
#pragma unroll
        for (int b = 0; b < N_BASIS; ++b) acc[b] = bpi1[c*N_BASIS + b];
#pragma unroll
        for (int k = 0; k < W; ++k) {
            float hk = h0[k];
#pragma unroll
            for (int b = 0; b < N_BASIS; ++b)
                acc[b] += hk * Wpi1[k*(W*N_BASIS) + c*N_BASIS + b];  // contiguous uniform -> s_load
        }
        float s = 0.0f;
#pragma unroll
        for (int b = 0; b < N_BASIS; ++b) s += fast_tanh(acc[b]) * bas[b];
        vbuf[threadIdx.x * W + c] = s;
    }

    float v[W];
#pragma unroll
    for (int c = 0; c < W; ++c) v[c] = vbuf[threadIdx.x * W + c];

    // ii: two bias-free 16x16 + tanh
    float u[W];
#pragma unroll
    for (int c = 0; c < W; ++c) u[c] = 0.0f;
#pragma unroll
    for (int k = 0; k < W; ++k)
#pragma unroll
        for (int c = 0; c < W; ++c) u[c] += v[k] * Wii0[k*W + c];
#pragma unroll
    for (int c = 0; c < W; ++c) u[c] = fast_tanh(u[c]);
    float w2[W];
#pragma unroll
    for (int c = 0; c < W; ++c) w2[c] = 0.0f;
#pragma unroll
    for (int k = 0; k < W; ++k)
#pragma unroll
        for (int c = 0; c < W; ++c) w2[c] += u[k] * Wii1[k*W + c];
#pragma unroll
    for (int c = 0; c < W; ++c) w2[c] = fast_tanh(w2[c]);

    float4* op = reinterpret_cast<float4*>(i_pair_out + (size_t)p * W);
    op[0] = make_float4(w2[0],  w2[1],  w2[2],  w2[3]);
    op[1] = make_float4(w2[4],  w2[5],  w2[6],  w2[7]);
    op[2] = make_float4(w2[8],  w2[9],  w2[10], w2[11]);
    op[3] = make_float4(w2[12], w2[13], w2[14], w2[15]);

#pragma unroll
    for (int c = 0; c < W; ++c) atomicAdd(&p_sum[(size_t)i * W + c], w2[c]);
}

// ---------------- pp_post: p1_new = tanh(tanh(p_sum@W0)@W1), no bias
__global__ __launch_bounds__(256) void k_pp_post(
    const float* __restrict__ p_sum,
    const float* __restrict__ W0, const float* __restrict__ W1,
    float* __restrict__ p1_new)
{
    int a = blockIdx.x * 256 + threadIdx.x;
    if (a >= N_ATOMS) return;
    const float4* src = reinterpret_cast<const float4*>(p_sum + (size_t)a * W);
    float4 v0 = src[0], v1 = src[1], v2 = src[2], v3 = src[3];
    float x[W] = {v0.x,v0.y,v0.z,v0.w, v1.x,v1.y,v1.z,v1.w,
                  v2.x,v2.y,v2.z,v2.w, v3.x,v3.y,v3.z,v3.w};
    float h[W];
#pragma unroll
    for (int c = 0; c < W; ++c) h[c] = 0.0f;
#pragma unroll
    for (int k = 0; k < W; ++k)
#pragma unroll
        for (int c = 0; c < W; ++c) h[c] += x[k] * W0[k*W + c];
#pragma unroll
    for (int c = 0; c < W; ++c) h[c] = fast_tanh(h[c]);
    float y[W];
#pragma unroll
    for (int c = 0; c < W; ++c) y[c] = 0.0f;
#pragma unroll
    for (int k = 0; k < W; ++k)
#pragma unroll
        for (int c = 0; c < W; ++c) y[c] += h[k] * W1[k*W + c];
    float4* dst = reinterpret_cast<float4*>(p1_new + (size_t)a * W);
    dst[0] = make_float4(fast_tanh(y[0]),  fast_tanh(y[1]),  fast_tanh(y[2]),  fast_tanh(y[3]));
    dst[1] = make_float4(fast_tanh(y[4]),  fast_tanh(y[5]),  fast_tanh(y[6]),  fast_tanh(y[7]));
    dst[2] = make_float4(fast_tanh(y[8]),  fast_tanh(y[9]),  fast_tanh(y[10]), fast_tanh(y[11]));
    dst[3] = make_float4(fast_tanh(y[12]), fast_tanh(y[13]), fast_tanh(y[14]), fast_tanh(y[15]));
}

extern "C" void kernel_launch(void* const* d_in, const int* in_sizes, int n_in,
                              void* d_out, int out_size, void* d_ws, size_t ws_size,
                              hipStream_t stream) {
    const int*   ind2   = (const int*)d_in[0];
    const float* p1     = (const float*)d_in[1];
    const float* basis  = (const float*)d_in[2];
    const float* Wpre0  = (const float*)d_in[3];
    const float* bpre0  = (const float*)d_in[4];
    const float* Wpre1  = (const float*)d_in[5];
    const float* bpre1  = (const float*)d_in[6];
    const float* Wpi0   = (const float*)d_in[7];
    const float* bpi0   = (const float*)d_in[8];
    const float* Wpi1   = (const float*)d_in[9];
    const float* bpi1   = (const float*)d_in[10];
    const float* Wii0   = (const float*)d_in[11];
    const float* Wii1   = (const float*)d_in[12];
    const float* Wpost0 = (const float*)d_in[13];
    const float* Wpost1 = (const float*)d_in[14];

    float* out    = (float*)d_out;
    float* p1_new = out;                          // (N_ATOMS, W)
    float* i_pair = out + (size_t)N_ATOMS * W;    // (N_PAIRS, W)

    float* p1_in = (float*)d_ws;                  // (N_ATOMS, W)
    float* p_sum = p1_in + (size_t)N_ATOMS * W;   // (N_ATOMS, W)

    hipMemsetAsync(p_sum, 0, (size_t)N_ATOMS * W * sizeof(float), stream);
    k_pp_pre<<<(N_ATOMS + 255) / 256, 256, 0, stream>>>(p1, Wpre0, bpre0, Wpre1, bpre1, p1_in);
    k_pair<<<N_PAIRS / 256, 256, 0, stream>>>(ind2, basis, p1_in,
                                              Wpi0, bpi0, Wpi1, bpi1, Wii0, Wii1,
                                              i_pair, p_sum);
    k_pp_post<<<(N_ATOMS + 255) / 256, 256, 0, stream>>>(p_sum, Wpost0, Wpost1, p1_new);
}

// Round 2
// 1074.839 us; speedup vs baseline: 2.5316x; 2.5316x over previous
//
#include <hip/hip_runtime.h>

#define N_ATOMS 100000
#define N_PAIRS 3200000
#define N_PROP 16
#define N_BASIS 10
#define W 16
#define NT (N_PAIRS / 16)   // 16-pair tiles

typedef short s16x8 __attribute__((ext_vector_type(8)));
typedef float f32x4 __attribute__((ext_vector_type(4)));

__device__ __forceinline__ float fast_tanh(float x) {
    float e = __builtin_amdgcn_exp2f(x * 2.88539008177792681f);
    return 1.0f - 2.0f * __builtin_amdgcn_rcpf(e + 1.0f);
}
__device__ __forceinline__ unsigned short bf16r(float f) {
    union { float f; unsigned u; } v; v.f = f;
    unsigned r = v.u + 0x7FFFu + ((v.u >> 16) & 1u);
    return (unsigned short)(r >> 16);
}
__device__ __forceinline__ float bf16f(unsigned short h) {
    union { unsigned u; float f; } v; v.u = ((unsigned)h) << 16; return v.f;
}

// ---------------- pp_pre (unchanged, f32 VALU; not a bottleneck)
__global__ __launch_bounds__(256) void k_pp_pre(
    const float* __restrict__ p1,
    const float* __restrict__ W0, const float* __restrict__ b0,
    const float* __restrict__ W1, const float* __restrict__ b1,
    float* __restrict__ p1_in)
{
    int a = blockIdx.x * 256 + threadIdx.x;
    if (a >= N_ATOMS) return;
    const float4* src = reinterpret_cast<const float4*>(p1 + (size_t)a * N_PROP);
    float4 v0 = src[0], v1 = src[1], v2 = src[2], v3 = src[3];
    float x[N_PROP] = {v0.x,v0.y,v0.z,v0.w, v1.x,v1.y,v1.z,v1.w,
                       v2.x,v2.y,v2.z,v2.w, v3.x,v3.y,v3.z,v3.w};
    float h[W];
#pragma unroll
    for (int c = 0; c < W; ++c) h[c] = b0[c];
#pragma unroll
    for (int k = 0; k < N_PROP; ++k)
#pragma unroll
        for (int c = 0; c < W; ++c) h[c] += x[k] * W0[k*W + c];
#pragma unroll
    for (int c = 0; c < W; ++c) h[c] = fast_tanh(h[c]);
    float y[W];
#pragma unroll
    for (int c = 0; c < W; ++c) y[c] = b1[c];
#pragma unroll
    for (int k = 0; k < W; ++k)
#pragma unroll
        for (int c = 0; c < W; ++c) y[c] += h[k] * W1[k*W + c];
    float4* dst = reinterpret_cast<float4*>(p1_in + (size_t)a * W);
    dst[0] = make_float4(fast_tanh(y[0]),  fast_tanh(y[1]),  fast_tanh(y[2]),  fast_tanh(y[3]));
    dst[1] = make_float4(fast_tanh(y[4]),  fast_tanh(y[5]),  fast_tanh(y[6]),  fast_tanh(y[7]));
    dst[2] = make_float4(fast_tanh(y[8]),  fast_tanh(y[9]),  fast_tanh(y[10]), fast_tanh(y[11]));
    dst[3] = make_float4(fast_tanh(y[12]), fast_tanh(y[13]), fast_tanh(y[14]), fast_tanh(y[15]));
}

// exchange C-layout (lane holds rows 4g+i of its pair column) -> B-layout
// (lane needs chans 8g+j of its pair), hi/lo bf16 split. 8 shfl, no divergence.
__device__ __forceinline__ void exch_to_B(float x0, float x1, float x2, float x3,
                                          int r, int g, bool augment,
                                          s16x8& Bh, s16x8& Bl)
{
    unsigned short h0 = bf16r(x0), h1 = bf16r(x1), h2 = bf16r(x2), h3 = bf16r(x3);
    unsigned hw0 = (unsigned)h0 | ((unsigned)h1 << 16);
    unsigned hw1 = (unsigned)h2 | ((unsigned)h3 << 16);
    unsigned short l0 = bf16r(x0 - bf16f(h0)), l1 = bf16r(x1 - bf16f(h1));
    unsigned short l2 = bf16r(x2 - bf16f(h2)), l3 = bf16r(x3 - bf16f(h3));
    unsigned lw0 = (unsigned)l0 | ((unsigned)l1 << 16);
    unsigned lw1 = (unsigned)l2 | ((unsigned)l3 << 16);
    int t0 = (r + 32*g) & 63, t1 = (r + 32*g + 16) & 63;
    unsigned bw0 = (unsigned)__shfl((int)hw0, t0);
    unsigned bw1 = (unsigned)__shfl((int)hw1, t0);
    unsigned bw2 = (unsigned)__shfl((int)hw0, t1);
    unsigned bw3 = (unsigned)__shfl((int)hw1, t1);
    unsigned cw0 = (unsigned)__shfl((int)lw0, t0);
    unsigned cw1 = (unsigned)__shfl((int)lw1, t0);
    unsigned cw2 = (unsigned)__shfl((int)lw0, t1);
    unsigned cw3 = (unsigned)__shfl((int)lw1, t1);
    if (g >= 2) {
        bw0 = (augment && g == 2) ? 0x3F80u : 0u;  // bf16(1.0) at k==16
        bw1 = bw2 = bw3 = 0u;
        cw0 = cw1 = cw2 = cw3 = 0u;
    }
    union { unsigned u[4]; s16x8 v; } ph, pl;
    ph.u[0] = bw0; ph.u[1] = bw1; ph.u[2] = bw2; ph.u[3] = bw3;
    pl.u[0] = cw0; pl.u[1] = cw1; pl.u[2] = cw2; pl.u[3] = cw3;
    Bh = ph.v; Bl = pl.v;
}

// ---------------- pair kernel: MFMA, 16 pairs per wave-tile, grid-stride
__global__ __launch_bounds__(256) void k_pair_mfma(
    const int*   __restrict__ ind2,
    const float* __restrict__ basis,
    const float* __restrict__ p1_in,
    const float* __restrict__ Wpi0, const float* __restrict__ bpi0,
    const float* __restrict__ Wpi1, const float* __restrict__ bpi1,
    const float* __restrict__ Wii0, const float* __restrict__ Wii1,
    float* __restrict__ i_pair_out)
{
    const int lane = threadIdx.x & 63;
    const int w    = threadIdx.x >> 6;
    const int r    = lane & 15;     // pair slot within tile (C column)
    const int g    = lane >> 4;     // 16-lane group

    // ---- weight fragments (A-layout: row = r, k = 8g+j), loaded once
    s16x8 a1, a3, a4;
#pragma unroll
    for (int j = 0; j < 8; ++j) {
        int k = 8*g + j;
        a1[j] = (short)bf16r(Wpi0[k*W + r]);                       // Wpi0^T
        a3[j] = (short)(k < W ? bf16r(Wii0[k*W + r]) : 0);         // Wii0^T (K pad)
        a4[j] = (short)(k < W ? bf16r(Wii1[k*W + r]) : 0);         // Wii1^T
    }
    // pi1 feature-permuted tiles: A-row r of tile t holds feature (cf*10+bp),
    // s = 4t+(r&3), cf = s/3, bp = (s%3)*4 + (r>>2); bp>=10 are zero pads.
    s16x8 a2[12];
#pragma unroll
    for (int t = 0; t < 12; ++t) {
        int s  = 4*t + (r & 3);
        int cf = s / 3;
        int bp = (s % 3) * 4 + (r >> 2);
#pragma unroll
        for (int j = 0; j < 8; ++j) {
            int k = 8*g + j;
            float wv = 0.0f;
            if (bp < N_BASIS) {
                if (k < W)       wv = Wpi1[k*(W*N_BASIS) + cf*N_BASIS + bp];
                else if (k == W) wv = bpi1[cf*N_BASIS + bp];   // augmented bias row
            }
            a2[t][j] = (short)bf16r(wv);
        }
    }
    float b0v[4];
#pragma unroll
    for (int i = 0; i < 4; ++i) b0v[i] = bpi0[4*g + i];

    for (int tile = blockIdx.x * 4 + w; tile < NT; tile += gridDim.x * 4) {
        const int p0 = tile * 16;
        int2 ij = reinterpret_cast<const int2*>(ind2)[p0 + r];
        int atom = (g < 2) ? ij.x : ij.y;

        // gather h^T fragment: lane (r,g) = 8 floats of row i/j, half (g&1)
        const float4* rp = reinterpret_cast<const float4*>(
            p1_in + (size_t)atom * W + (g & 1) * 8);
        float4 f0 = rp[0], f1 = rp[1];
        float hv[8] = {f0.x,f0.y,f0.z,f0.w, f1.x,f1.y,f1.z,f1.w};
        s16x8 B1h, B1l;
#pragma unroll
        for (int j = 0; j < 8; ++j) {
            unsigned short hb = bf16r(hv[j]);
            B1h[j] = (short)hb;
            B1l[j] = (short)bf16r(hv[j] - bf16f(hb));
        }

        // basis slices for this lane: bas3[m] = basis[p][4m+g] (pad 0 for >=10)
        const float* bb = basis + (size_t)(p0 + r) * N_BASIS;
        float bas3_0 = bb[g];
        float bas3_1 = bb[4 + g];
        float bas3_2 = (g < 2) ? bb[8 + g] : 0.0f;

        // ---- pi0: D[c][p] = Wpi0^T @ h^T  (K=32), act-split hi/lo
        f32x4 acc = {0.f, 0.f, 0.f, 0.f};
        acc = __builtin_amdgcn_mfma_f32_16x16x32_bf16(a1, B1h, acc, 0, 0, 0);
        acc = __builtin_amdgcn_mfma_f32_16x16x32_bf16(a1, B1l, acc, 0, 0, 0);
        float h0v[4];
#pragma unroll
        for (int i = 0; i < 4; ++i) h0v[i] = fast_tanh(acc[i] + b0v[i]);

        // redistribute h0 to B-layout (augment k=16 with 1.0 for bias row)
        s16x8 B2h, B2l;
        exch_to_B(h0v[0], h0v[1], h0v[2], h0v[3], r, g, true, B2h, B2l);

        // ---- pi1 (12 permuted tiles) + tanh + basis contraction (f32)
        float vpart[16];
#pragma unroll
        for (int c = 0; c < 16; ++c) vpart[c] = 0.0f;
#pragma unroll
        for (int t = 0; t < 12; ++t) {
            f32x4 z = {0.f, 0.f, 0.f, 0.f};
            z = __builtin_amdgcn_mfma_f32_16x16x32_bf16(a2[t], B2h, z, 0, 0, 0);
            z = __builtin_amdgcn_mfma_f32_16x16x32_bf16(a2[t], B2l, z, 0, 0, 0);
#pragma unroll
            for (int i = 0; i < 4; ++i) {
                const int s = 4*t + i;          // compile-time
                const int c = s / 3;            // static accumulator index
                const int m = s % 3;            // static basis slice
                float tz = fast_tanh(z[i]);
                if (m == 0)      vpart[c] += tz * bas3_0;
                else if (m == 1) vpart[c] += tz * bas3_1;
                else             vpart[c] += tz * bas3_2;
            }
        }
        // reduce partial v over the 4 g-groups (butterfly)
#pragma unroll
        for (int c = 0; c < 16; ++c) {
            vpart[c] += __shfl_xor(vpart[c], 16);
            vpart[c] += __shfl_xor(vpart[c], 32);
        }
        // pick this lane's 8 channels (static branches, no runtime indexing)
        float vv[8];
        if (g == 0) {
#pragma unroll
            for (int j = 0; j < 8; ++j) vv[j] = vpart[j];
        } else if (g == 1) {
#pragma unroll
            for (int j = 0; j < 8; ++j) vv[j] = vpart[8 + j];
        } else {
#pragma unroll
            for (int j = 0; j < 8; ++j) vv[j] = 0.0f;
        }
        s16x8 B3h, B3l;
#pragma unroll
        for (int j = 0; j < 8; ++j) {
            unsigned short hb = bf16r(vv[j]);
            B3h[j] = (short)hb;
            B3l[j] = (short)bf16r(vv[j] - bf16f(hb));
        }

        // ---- ii0
        f32x4 ua = {0.f, 0.f, 0.f, 0.f};
        ua = __builtin_amdgcn_mfma_f32_16x16x32_bf16(a3, B3h, ua, 0, 0, 0);
        ua = __builtin_amdgcn_mfma_f32_16x16x32_bf16(a3, B3l, ua, 0, 0, 0);
        float uv0 = fast_tanh(ua[0]), uv1 = fast_tanh(ua[1]);
        float uv2 = fast_tanh(ua[2]), uv3 = fast_tanh(ua[3]);
        s16x8 B4h, B4l;
        exch_to_B(uv0, uv1, uv2, uv3, r, g, false, B4h, B4l);

        // ---- ii1
        f32x4 wa = {0.f, 0.f, 0.f, 0.f};
        wa = __builtin_amdgcn_mfma_f32_16x16x32_bf16(a4, B4h, wa, 0, 0, 0);
        wa = __builtin_amdgcn_mfma_f32_16x16x32_bf16(a4, B4l, wa, 0, 0, 0);
        float4 outv = make_float4(fast_tanh(wa[0]), fast_tanh(wa[1]),
                                  fast_tanh(wa[2]), fast_tanh(wa[3]));
        *reinterpret_cast<float4*>(i_pair_out + (size_t)(p0 + r) * W + 4*g) = outv;
    }
}

// ---------------- scatter-free IP: count / scan / bucket / reduce
__global__ __launch_bounds__(256) void k_count(const int* __restrict__ ind2,
                                               unsigned* __restrict__ counts)
{
    int p = blockIdx.x * 256 + threadIdx.x;
    if (p >= N_PAIRS) return;
    atomicAdd(&counts[ind2[2*p]], 1u);
}

__global__ __launch_bounds__(1024) void k_scan(const unsigned* __restrict__ counts,
                                               unsigned* __restrict__ starts,
                                               unsigned* __restrict__ cursor)
{
    __shared__ unsigned partial[1024];
    const int CH = (N_ATOMS + 1023) / 1024;   // 98
    int t = threadIdx.x;
    int a0 = t * CH, a1 = min(a0 + CH, N_ATOMS);
    unsigned s = 0;
    for (int a = a0; a < a1; ++a) s += counts[a];
    partial[t] = s;
    __syncthreads();
    for (int off = 1; off < 1024; off <<= 1) {
        unsigned v = partial[t];
        unsigned add = (t >= off) ? partial[t - off] : 0u;
        __syncthreads();
        partial[t] = v + add;
        __syncthreads();
    }
    unsigned run = (t == 0) ? 0u : partial[t - 1];
    for (int a = a0; a < a1; ++a) {
        starts[a] = run; cursor[a] = run;
        run += counts[a];
    }
}

__global__ __launch_bounds__(256) void k_fill(const int* __restrict__ ind2,
                                              unsigned* __restrict__ cursor,
                                              unsigned* __restrict__ bucket)
{
    int p = blockIdx.x * 256 + threadIdx.x;
    if (p >= N_PAIRS) return;
    unsigned pos = atomicAdd(&cursor[ind2[2*p]], 1u);
    bucket[pos] = (unsigned)p;
}

__global__ __launch_bounds__(256) void k_reduce(const unsigned* __restrict__ starts,
                                                const unsigned* __restrict__ counts,
                                                const unsigned* __restrict__ bucket,
                                                const float* __restrict__ i_pair,
                                                float* __restrict__ p_sum)
{
    int wave = blockIdx.x * 4 + (threadIdx.x >> 6);
    if (wave >= N_ATOMS) return;
    int lane = threadIdx.x & 63;
    int c = lane & 15, q = lane >> 4;
    unsigned n = counts[wave], st = starts[wave];
    float acc = 0.0f;
    for (unsigned k = q; k < n; k += 4) {
        unsigned pid = bucket[st + k];
        acc += i_pair[(size_t)pid * W + c];
    }
    acc += __shfl_xor(acc, 16);
    acc += __shfl_xor(acc, 32);
    if (q == 0) p_sum[(size_t)wave * W + c] = acc;
}

// ---------------- pp_post (unchanged)
__global__ __launch_bounds__(256) void k_pp_post(
    const float* __restrict__ p_sum,
    const float* __restrict__ W0, const float* __restrict__ W1,
    float* __restrict__ p1_new)
{
    int a = blockIdx.x * 256 + threadIdx.x;
    if (a >= N_ATOMS) return;
    const float4* src = reinterpret_cast<const float4*>(p_sum + (size_t)a * W);
    float4 v0 = src[0], v1 = src[1], v2 = src[2], v3 = src[3];
    float x[W] = {v0.x,v0.y,v0.z,v0.w, v1.x,v1.y,v1.z,v1.w,
                  v2.x,v2.y,v2.z,v2.w, v3.x,v3.y,v3.z,v3.w};
    float h[W];
#pragma unroll
    for (int c = 0; c < W; ++c) h[c] = 0.0f;
#pragma unroll
    for (int k = 0; k < W; ++k)
#pragma unroll
        for (int c = 0; c < W; ++c) h[c] += x[k] * W0[k*W + c];
#pragma unroll
    for (int c = 0; c < W; ++c) h[c] = fast_tanh(h[c]);
    float y[W];
#pragma unroll
    for (int c = 0; c < W; ++c) y[c] = 0.0f;
#pragma unroll
    for (int k = 0; k < W; ++k)
#pragma unroll
        for (int c = 0; c < W; ++c) y[c] += h[k] * W1[k*W + c];
    float4* dst = reinterpret_cast<float4*>(p1_new + (size_t)a * W);
    dst[0] = make_float4(fast_tanh(y[0]),  fast_tanh(y[1]),  fast_tanh(y[2]),  fast_tanh(y[3]));
    dst[1] = make_float4(fast_tanh(y[4]),  fast_tanh(y[5]),  fast_tanh(y[6]),  fast_tanh(y[7]));
    dst[2] = make_float4(fast_tanh(y[8]),  fast_tanh(y[9]),  fast_tanh(y[10]), fast_tanh(y[11]));
    dst[3] = make_float4(fast_tanh(y[12]), fast_tanh(y[13]), fast_tanh(y[14]), fast_tanh(y[15]));
}

extern "C" void kernel_launch(void* const* d_in, const int* in_sizes, int n_in,
                              void* d_out, int out_size, void* d_ws, size_t ws_size,
                              hipStream_t stream) {
    const int*   ind2   = (const int*)d_in[0];
    const float* p1     = (const float*)d_in[1];
    const float* basis  = (const float*)d_in[2];
    const float* Wpre0  = (const float*)d_in[3];
    const float* bpre0  = (const float*)d_in[4];
    const float* Wpre1  = (const float*)d_in[5];
    const float* bpre1  = (const float*)d_in[6];
    const float* Wpi0   = (const float*)d_in[7];
    const float* bpi0   = (const float*)d_in[8];
    const float* Wpi1   = (const float*)d_in[9];
    const float* bpi1   = (const float*)d_in[10];
    const float* Wii0   = (const float*)d_in[11];
    const float* Wii1   = (const float*)d_in[12];
    const float* Wpost0 = (const float*)d_in[13];
    const float* Wpost1 = (const float*)d_in[14];

    float* out    = (float*)d_out;
    float* p1_new = out;                          // (N_ATOMS, W)
    float* i_pair = out + (size_t)N_ATOMS * W;    // (N_PAIRS, W)

    float*    p1_in  = (float*)d_ws;                            // 1.6M f32
    float*    p_sum  = p1_in + (size_t)N_ATOMS * W;             // 1.6M f32
    unsigned* counts = (unsigned*)(p_sum + (size_t)N_ATOMS * W);// 100k u32
    unsigned* starts = counts + N_ATOMS;                        // 100k
    unsigned* cursor = starts + N_ATOMS;                        // 100k
    unsigned* bucket = cursor + N_ATOMS;                        // 3.2M

    hipMemsetAsync(counts, 0, (size_t)N_ATOMS * sizeof(unsigned), stream);
    k_pp_pre<<<(N_ATOMS + 255) / 256, 256, 0, stream>>>(p1, Wpre0, bpre0, Wpre1, bpre1, p1_in);
    k_count<<<(N_PAIRS + 255) / 256, 256, 0, stream>>>(ind2, counts);
    k_scan<<<1, 1024, 0, stream>>>(counts, starts, cursor);
    k_fill<<<(N_PAIRS + 255) / 256, 256, 0, stream>>>(ind2, cursor, bucket);
    k_pair_mfma<<<2560, 256, 0, stream>>>(ind2, basis, p1_in,
                                          Wpi0, bpi0, Wpi1, bpi1, Wii0, Wii1,
                                          i_pair);
    k_reduce<<<(N_ATOMS + 3) / 4, 256, 0, stream>>>(starts, counts, bucket, i_pair, p_sum);
    k_pp_post<<<(N_ATOMS + 255) / 256, 256, 0, stream>>>(p_sum, Wpost0, Wpost1, p1_new);
}

// Round 3
// 894.468 us; speedup vs baseline: 3.0421x; 1.2017x over previous
//
#include <hip/hip_runtime.h>

#define N_ATOMS 100000
#define N_PAIRS 3200000
#define N_PROP 16
#define N_BASIS 10
#define W 16
#define NT (N_PAIRS / 16)   // 16-pair tiles

typedef short  s16x8 __attribute__((ext_vector_type(8)));
typedef float  f32x4 __attribute__((ext_vector_type(4)));

__device__ __forceinline__ float fast_tanh(float x) {
    float e = __builtin_amdgcn_exp2f(x * 2.88539008177792681f);
    return 1.0f - 2.0f * __builtin_amdgcn_rcpf(e + 1.0f);
}
__device__ __forceinline__ unsigned short bf16r(float f) {
    union { float f; unsigned u; } v; v.f = f;
    unsigned r = v.u + 0x7FFFu + ((v.u >> 16) & 1u);
    return (unsigned short)(r >> 16);
}
__device__ __forceinline__ float bf16f(unsigned short h) {
    union { unsigned u; float f; } v; v.u = ((unsigned)h) << 16; return v.f;
}

// ---------------- pp_pre: also emits bf16 hi/lo split of p1_in
__global__ __launch_bounds__(256) void k_pp_pre(
    const float* __restrict__ p1,
    const float* __restrict__ W0, const float* __restrict__ b0,
    const float* __restrict__ W1, const float* __restrict__ b1,
    unsigned short* __restrict__ p1h, unsigned short* __restrict__ p1l)
{
    int a = blockIdx.x * 256 + threadIdx.x;
    if (a >= N_ATOMS) return;
    const float4* src = reinterpret_cast<const float4*>(p1 + (size_t)a * N_PROP);
    float4 v0 = src[0], v1 = src[1], v2 = src[2], v3 = src[3];
    float x[N_PROP] = {v0.x,v0.y,v0.z,v0.w, v1.x,v1.y,v1.z,v1.w,
                       v2.x,v2.y,v2.z,v2.w, v3.x,v3.y,v3.z,v3.w};
    float h[W];
#pragma unroll
    for (int c = 0; c < W; ++c) h[c] = b0[c];
#pragma unroll
    for (int k = 0; k < N_PROP; ++k)
#pragma unroll
        for (int c = 0; c < W; ++c) h[c] += x[k] * W0[k*W + c];
#pragma unroll
    for (int c = 0; c < W; ++c) h[c] = fast_tanh(h[c]);
    float y[W];
#pragma unroll
    for (int c = 0; c < W; ++c) y[c] = b1[c];
#pragma unroll
    for (int k = 0; k < W; ++k)
#pragma unroll
        for (int c = 0; c < W; ++c) y[c] += h[k] * W1[k*W + c];
    union { unsigned short u[8]; s16x8 v; } hi0, hi1, lo0, lo1;
#pragma unroll
    for (int c = 0; c < W; ++c) {
        float t = fast_tanh(y[c]);
        unsigned short hb = bf16r(t);
        unsigned short lb = bf16r(t - bf16f(hb));
        if (c < 8) { hi0.u[c] = hb; lo0.u[c] = lb; }
        else       { hi1.u[c-8] = hb; lo1.u[c-8] = lb; }
    }
    s16x8* dh = reinterpret_cast<s16x8*>(p1h + (size_t)a * W);
    s16x8* dl = reinterpret_cast<s16x8*>(p1l + (size_t)a * W);
    dh[0] = hi0.v; dh[1] = hi1.v;
    dl[0] = lo0.v; dl[1] = lo1.v;
}

// C-layout (lane holds rows 4g+i of pair column r) -> B-layout (lane needs ch 8g+j), hi/lo
__device__ __forceinline__ void exch_to_B(float x0, float x1, float x2, float x3,
                                          int r, int g, bool augment,
                                          s16x8& Bh, s16x8& Bl)
{
    unsigned short h0 = bf16r(x0), h1 = bf16r(x1), h2 = bf16r(x2), h3 = bf16r(x3);
    unsigned hw0 = (unsigned)h0 | ((unsigned)h1 << 16);
    unsigned hw1 = (unsigned)h2 | ((unsigned)h3 << 16);
    unsigned short l0 = bf16r(x0 - bf16f(h0)), l1 = bf16r(x1 - bf16f(h1));
    unsigned short l2 = bf16r(x2 - bf16f(h2)), l3 = bf16r(x3 - bf16f(h3));
    unsigned lw0 = (unsigned)l0 | ((unsigned)l1 << 16);
    unsigned lw1 = (unsigned)l2 | ((unsigned)l3 << 16);
    int t0 = (r + 32*g) & 63, t1 = (r + 32*g + 16) & 63;
    unsigned bw0 = (unsigned)__shfl((int)hw0, t0);
    unsigned bw1 = (unsigned)__shfl((int)hw1, t0);
    unsigned bw2 = (unsigned)__shfl((int)hw0, t1);
    unsigned bw3 = (unsigned)__shfl((int)hw1, t1);
    unsigned cw0 = (unsigned)__shfl((int)lw0, t0);
    unsigned cw1 = (unsigned)__shfl((int)lw1, t0);
    unsigned cw2 = (unsigned)__shfl((int)lw0, t1);
    unsigned cw3 = (unsigned)__shfl((int)lw1, t1);
    if (g >= 2) {
        bw0 = (augment && g == 2) ? 0x3F80u : 0u;
        bw1 = bw2 = bw3 = 0u;
        cw0 = cw1 = cw2 = cw3 = 0u;
    }
    union { unsigned u[4]; s16x8 v; } ph, pl;
    ph.u[0] = bw0; ph.u[1] = bw1; ph.u[2] = bw2; ph.u[3] = bw3;
    pl.u[0] = cw0; pl.u[1] = cw1; pl.u[2] = cw2; pl.u[3] = cw3;
    Bh = ph.v; Bl = pl.v;
}

// hi-only variant (no bias augment)
__device__ __forceinline__ s16x8 exch_hi(float x0, float x1, float x2, float x3,
                                         int r, int g)
{
    unsigned short h0 = bf16r(x0), h1 = bf16r(x1), h2 = bf16r(x2), h3 = bf16r(x3);
    unsigned hw0 = (unsigned)h0 | ((unsigned)h1 << 16);
    unsigned hw1 = (unsigned)h2 | ((unsigned)h3 << 16);
    int t0 = (r + 32*g) & 63, t1 = (r + 32*g + 16) & 63;
    unsigned bw0 = (unsigned)__shfl((int)hw0, t0);
    unsigned bw1 = (unsigned)__shfl((int)hw1, t0);
    unsigned bw2 = (unsigned)__shfl((int)hw0, t1);
    unsigned bw3 = (unsigned)__shfl((int)hw1, t1);
    if (g >= 2) { bw0 = bw1 = bw2 = bw3 = 0u; }
    union { unsigned u[4]; s16x8 v; } ph;
    ph.u[0] = bw0; ph.u[1] = bw1; ph.u[2] = bw2; ph.u[3] = bw3;
    return ph.v;
}

// ---------------- pair kernel
template<int SORTED>
__global__ __launch_bounds__(256) void k_pair_mfma(
    const int*   __restrict__ ind2,
    const float* __restrict__ basis,
    const unsigned short* __restrict__ p1h,
    const unsigned short* __restrict__ p1l,
    const float* __restrict__ Wpi0, const float* __restrict__ bpi0,
    const float* __restrict__ Wpi1, const float* __restrict__ bpi1,
    const float* __restrict__ Wii0, const float* __restrict__ Wii1,
    float* __restrict__ i_pair_out,
    unsigned* __restrict__ cursor, float* __restrict__ svals)
{
    const int lane = threadIdx.x & 63;
    const int w    = threadIdx.x >> 6;
    const int r    = lane & 15;
    const int g    = lane >> 4;

    s16x8 a1, a3, a4;
#pragma unroll
    for (int j = 0; j < 8; ++j) {
        int k = 8*g + j;
        a1[j] = (short)bf16r(Wpi0[k*W + r]);
        a3[j] = (short)(k < W ? bf16r(Wii0[k*W + r]) : 0);
        a4[j] = (short)(k < W ? bf16r(Wii1[k*W + r]) : 0);
    }
    s16x8 a2[12];
#pragma unroll
    for (int t = 0; t < 12; ++t) {
        int s  = 4*t + (r & 3);
        int cf = s / 3;
        int bp = (s % 3) * 4 + (r >> 2);
#pragma unroll
        for (int j = 0; j < 8; ++j) {
            int k = 8*g + j;
            float wv = 0.0f;
            if (bp < N_BASIS) {
                if (k < W)       wv = Wpi1[k*(W*N_BASIS) + cf*N_BASIS + bp];
                else if (k == W) wv = bpi1[cf*N_BASIS + bp];
            }
            a2[t][j] = (short)bf16r(wv);
        }
    }
    float b0v[4];
#pragma unroll
    for (int i = 0; i < 4; ++i) b0v[i] = bpi0[4*g + i];

    for (int tile = blockIdx.x * 4 + w; tile < NT; tile += gridDim.x * 4) {
        const int p0 = tile * 16;
        int2 ij = reinterpret_cast<const int2*>(ind2)[p0 + r];
        int atom = (g < 2) ? ij.x : ij.y;

        const s16x8 B1h = *reinterpret_cast<const s16x8*>(p1h + (size_t)atom * W + (g & 1) * 8);
        const s16x8 B1l = *reinterpret_cast<const s16x8*>(p1l + (size_t)atom * W + (g & 1) * 8);

        const float* bb = basis + (size_t)(p0 + r) * N_BASIS;
        float bas3_0 = bb[g];
        float bas3_1 = bb[4 + g];
        float bas3_2 = (g < 2) ? bb[8 + g] : 0.0f;

        // pi0 (K=32), hi/lo
        f32x4 acc = {0.f, 0.f, 0.f, 0.f};
        acc = __builtin_amdgcn_mfma_f32_16x16x32_bf16(a1, B1h, acc, 0, 0, 0);
        acc = __builtin_amdgcn_mfma_f32_16x16x32_bf16(a1, B1l, acc, 0, 0, 0);
        float h0v[4];
#pragma unroll
        for (int i = 0; i < 4; ++i) h0v[i] = fast_tanh(acc[i] + b0v[i]);

        s16x8 B2h, B2l;
        exch_to_B(h0v[0], h0v[1], h0v[2], h0v[3], r, g, true, B2h, B2l);

        // pi1: 12 permuted tiles, hi/lo, tanh + basis contraction
        float vpart[16];
#pragma unroll
        for (int c = 0; c < 16; ++c) vpart[c] = 0.0f;
#pragma unroll
        for (int t = 0; t < 12; ++t) {
            f32x4 z = {0.f, 0.f, 0.f, 0.f};
            z = __builtin_amdgcn_mfma_f32_16x16x32_bf16(a2[t], B2h, z, 0, 0, 0);
            z = __builtin_amdgcn_mfma_f32_16x16x32_bf16(a2[t], B2l, z, 0, 0, 0);
#pragma unroll
            for (int i = 0; i < 4; ++i) {
                const int s = 4*t + i;
                const int c = s / 3;
                const int m = s % 3;
                float tz = fast_tanh(z[i]);
                if (m == 0)      vpart[c] += tz * bas3_0;
                else if (m == 1) vpart[c] += tz * bas3_1;
                else             vpart[c] += tz * bas3_2;
            }
        }
#pragma unroll
        for (int c = 0; c < 16; ++c) {
            vpart[c] += __shfl_xor(vpart[c], 16);
            vpart[c] += __shfl_xor(vpart[c], 32);
        }
        // B3: single bf16 (static per-g selection, no shfl)
        s16x8 B3h;
#pragma unroll
        for (int j = 0; j < 8; ++j) {
            float vv = (g == 0) ? vpart[j] : (g == 1) ? vpart[8 + j] : 0.0f;
            B3h[j] = (short)bf16r(vv);
        }

        // ii0 (1 MFMA)
        f32x4 ua = {0.f, 0.f, 0.f, 0.f};
        ua = __builtin_amdgcn_mfma_f32_16x16x32_bf16(a3, B3h, ua, 0, 0, 0);
        s16x8 B4h = exch_hi(fast_tanh(ua[0]), fast_tanh(ua[1]),
                            fast_tanh(ua[2]), fast_tanh(ua[3]), r, g);

        // ii1 (1 MFMA)
        f32x4 wa = {0.f, 0.f, 0.f, 0.f};
        wa = __builtin_amdgcn_mfma_f32_16x16x32_bf16(a4, B4h, wa, 0, 0, 0);
        float4 outv = make_float4(fast_tanh(wa[0]), fast_tanh(wa[1]),
                                  fast_tanh(wa[2]), fast_tanh(wa[3]));
        *reinterpret_cast<float4*>(i_pair_out + (size_t)(p0 + r) * W + 4*g) = outv;

        if (SORTED) {
            unsigned pos = 0;
            if (g == 0) pos = atomicAdd(&cursor[ij.x], 1u);
            pos = (unsigned)__shfl((int)pos, r);
            *reinterpret_cast<float4*>(svals + (size_t)pos * W + 4*g) = outv;
        }
    }
}

// ---------------- IP pipeline
__global__ __launch_bounds__(256) void k_count(const int* __restrict__ ind2,
                                               unsigned* __restrict__ counts)
{
    int p = blockIdx.x * 256 + threadIdx.x;
    if (p >= N_PAIRS) return;
    atomicAdd(&counts[ind2[2*p]], 1u);
}

__global__ __launch_bounds__(1024) void k_scan(const unsigned* __restrict__ counts,
                                               unsigned* __restrict__ starts,
                                               unsigned* __restrict__ cursor)
{
    __shared__ unsigned partial[1024];
    const int CH = (N_ATOMS + 1023) / 1024;
    int t = threadIdx.x;
    int a0 = t * CH, a1 = min(a0 + CH, N_ATOMS);
    unsigned s = 0;
    for (int a = a0; a < a1; ++a) s += counts[a];
    partial[t] = s;
    __syncthreads();
    for (int off = 1; off < 1024; off <<= 1) {
        unsigned v = partial[t];
        unsigned add = (t >= off) ? partial[t - off] : 0u;
        __syncthreads();
        partial[t] = v + add;
        __syncthreads();
    }
    unsigned run = (t == 0) ? 0u : partial[t - 1];
    for (int a = a0; a < a1; ++a) {
        starts[a] = run; cursor[a] = run;
        run += counts[a];
    }
}

// fallback path (small ws): explicit fill + gather reduce
__global__ __launch_bounds__(256) void k_fill(const int* __restrict__ ind2,
                                              unsigned* __restrict__ cursor,
                                              unsigned* __restrict__ bucket)
{
    int p = blockIdx.x * 256 + threadIdx.x;
    if (p >= N_PAIRS) return;
    unsigned pos = atomicAdd(&cursor[ind2[2*p]], 1u);
    bucket[pos] = (unsigned)p;
}

__global__ __launch_bounds__(256) void k_reduce_gather(const unsigned* __restrict__ starts,
                                                       const unsigned* __restrict__ counts,
                                                       const unsigned* __restrict__ bucket,
                                                       const float* __restrict__ i_pair,
                                                       float* __restrict__ p_sum)
{
    int a = blockIdx.x * 4 + (threadIdx.x >> 6);
    if (a >= N_ATOMS) return;
    int lane = threadIdx.x & 63;
    int c = lane & 15, q = lane >> 4;
    unsigned n = counts[a], st = starts[a];
    float acc = 0.0f;
    for (unsigned k = q; k < n; k += 4) {
        unsigned pid = bucket[st + k];
        acc += i_pair[(size_t)pid * W + c];
    }
    acc += __shfl_xor(acc, 16);
    acc += __shfl_xor(acc, 32);
    if (q == 0) p_sum[(size_t)a * W + c] = acc;
}

// streaming reduce over sorted values
__global__ __launch_bounds__(256) void k_reduce_stream(const unsigned* __restrict__ starts,
                                                       const unsigned* __restrict__ counts,
                                                       const float* __restrict__ svals,
                                                       float* __restrict__ p_sum)
{
    int a = blockIdx.x * 4 + (threadIdx.x >> 6);
    if (a >= N_ATOMS) return;
    int lane = threadIdx.x & 63;
    int c = lane & 15, q = lane >> 4;
    unsigned n = counts[a], st = starts[a];
    float acc = 0.0f;
    for (unsigned k = q; k < n; k += 4)
        acc += svals[(size_t)(st + k) * W + c];
    acc += __shfl_xor(acc, 16);
    acc += __shfl_xor(acc, 32);
    if (q == 0) p_sum[(size_t)a * W + c] = acc;
}

// ---------------- pp_post
__global__ __launch_bounds__(256) void k_pp_post(
    const float* __restrict__ p_sum,
    const float* __restrict__ W0, const float* __restrict__ W1,
    float* __restrict__ p1_new)
{
    int a = blockIdx.x * 256 + threadIdx.x;
    if (a >= N_ATOMS) return;
    const float4* src = reinterpret_cast<const float4*>(p_sum + (size_t)a * W);
    float4 v0 = src[0], v1 = src[1], v2 = src[2], v3 = src[3];
    float x[W] = {v0.x,v0.y,v0.z,v0.w, v1.x,v1.y,v1.z,v1.w,
                  v2.x,v2.y,v2.z,v2.w, v3.x,v3.y,v3.z,v3.w};
    float h[W];
#pragma unroll
    for (int c = 0; c < W; ++c) h[c] = 0.0f;
#pragma unroll
    for (int k = 0; k < W; ++k)
#pragma unroll
        for (int c = 0; c < W; ++c) h[c] += x[k] * W0[k*W + c];
#pragma unroll
    for (int c = 0; c < W; ++c) h[c] = fast_tanh(h[c]);
    float y[W];
#pragma unroll
    for (int c = 0; c < W; ++c) y[c] = 0.0f;
#pragma unroll
    for (int k = 0; k < W; ++k)
#pragma unroll
        for (int c = 0; c < W; ++c) y[c] += h[k] * W1[k*W + c];
    float4* dst = reinterpret_cast<float4*>(p1_new + (size_t)a * W);
    dst[0] = make_float4(fast_tanh(y[0]),  fast_tanh(y[1]),  fast_tanh(y[2]),  fast_tanh(y[3]));
    dst[1] = make_float4(fast_tanh(y[4]),  fast_tanh(y[5]),  fast_tanh(y[6]),  fast_tanh(y[7]));
    dst[2] = make_float4(fast_tanh(y[8]),  fast_tanh(y[9]),  fast_tanh(y[10]), fast_tanh(y[11]));
    dst[3] = make_float4(fast_tanh(y[12]), fast_tanh(y[13]), fast_tanh(y[14]), fast_tanh(y[15]));
}

extern "C" void kernel_launch(void* const* d_in, const int* in_sizes, int n_in,
                              void* d_out, int out_size, void* d_ws, size_t ws_size,
                              hipStream_t stream) {
    const int*   ind2   = (const int*)d_in[0];
    const float* p1     = (const float*)d_in[1];
    const float* basis  = (const float*)d_in[2];
    const float* Wpre0  = (const float*)d_in[3];
    const float* bpre0  = (const float*)d_in[4];
    const float* Wpre1  = (const float*)d_in[5];
    const float* bpre1  = (const float*)d_in[6];
    const float* Wpi0   = (const float*)d_in[7];
    const float* bpi0   = (const float*)d_in[8];
    const float* Wpi1   = (const float*)d_in[9];
    const float* bpi1   = (const float*)d_in[10];
    const float* Wii0   = (const float*)d_in[11];
    const float* Wii1   = (const float*)d_in[12];
    const float* Wpost0 = (const float*)d_in[13];
    const float* Wpost1 = (const float*)d_in[14];

    float* out    = (float*)d_out;
    float* p1_new = out;                          // (N_ATOMS, W)
    float* i_pair = out + (size_t)N_ATOMS * W;    // (N_PAIRS, W)

    char* ws = (char*)d_ws;
    unsigned short* p1h = (unsigned short*)ws;                    ws += (size_t)N_ATOMS * W * 2;
    unsigned short* p1l = (unsigned short*)ws;                    ws += (size_t)N_ATOMS * W * 2;
    float*    p_sum  = (float*)ws;                                ws += (size_t)N_ATOMS * W * 4;
    unsigned* counts = (unsigned*)ws;                             ws += (size_t)N_ATOMS * 4;
    unsigned* starts = (unsigned*)ws;                             ws += (size_t)N_ATOMS * 4;
    unsigned* cursor = (unsigned*)ws;                             ws += (size_t)N_ATOMS * 4;
    float*    svals  = (float*)ws;   // sorted copy: N_PAIRS*W f32 (204.8 MB)
    unsigned* bucket = (unsigned*)ws;

    size_t base_bytes  = (size_t)(ws - (char*)d_ws);
    size_t svals_bytes = (size_t)N_PAIRS * W * sizeof(float);
    int use_sorted = (ws_size >= base_bytes + svals_bytes);

    hipMemsetAsync(counts, 0, (size_t)N_ATOMS * sizeof(unsigned), stream);
    k_pp_pre<<<(N_ATOMS + 255) / 256, 256, 0, stream>>>(p1, Wpre0, bpre0, Wpre1, bpre1, p1h, p1l);
    k_count<<<(N_PAIRS + 255) / 256, 256, 0, stream>>>(ind2, counts);
    k_scan<<<1, 1024, 0, stream>>>(counts, starts, cursor);

    if (use_sorted) {
        k_pair_mfma<1><<<2560, 256, 0, stream>>>(ind2, basis, p1h, p1l,
                                                 Wpi0, bpi0, Wpi1, bpi1, Wii0, Wii1,
                                                 i_pair, cursor, svals);
        k_reduce_stream<<<(N_ATOMS + 3) / 4, 256, 0, stream>>>(starts, counts, svals, p_sum);
    } else {
        k_fill<<<(N_PAIRS + 255) / 256, 256, 0, stream>>>(ind2, cursor, bucket);
        k_pair_mfma<0><<<2560, 256, 0, stream>>>(ind2, basis, p1h, p1l,
                                                 Wpi0, bpi0, Wpi1, bpi1, Wii0, Wii1,
                                                 i_pair, cursor, svals);
        k_reduce_gather<<<(N_ATOMS + 3) / 4, 256, 0, stream>>>(starts, counts, bucket, i_pair, p_sum);
    }
    k_pp_post<<<(N_ATOMS + 255) / 256, 256, 0, stream>>>(p_sum, Wpost0, Wpost1, p1_new);
}

// Round 4
// 581.055 us; speedup vs baseline: 4.6830x; 1.5394x over previous
//
#include <hip/hip_runtime.h>

#define N_ATOMS 100000
#define N_PAIRS 3200000
#define N_PROP 16
#define N_BASIS 10
#define W 16
#define NT (N_PAIRS / 16)   // 16-pair tiles
#define SCAN_BLK 1024
#define NB ((N_ATOMS + SCAN_BLK - 1) / SCAN_BLK)   // 98

typedef short  s16x8 __attribute__((ext_vector_type(8)));
typedef float  f32x4 __attribute__((ext_vector_type(4)));

__device__ __forceinline__ float fast_tanh(float x) {
    float e = __builtin_amdgcn_exp2f(x * 2.88539008177792681f);
    return 1.0f - 2.0f * __builtin_amdgcn_rcpf(e + 1.0f);
}
__device__ __forceinline__ unsigned short bf16r(float f) {
    union { float f; unsigned u; } v; v.f = f;
    unsigned r = v.u + 0x7FFFu + ((v.u >> 16) & 1u);
    return (unsigned short)(r >> 16);
}
__device__ __forceinline__ float bf16f(unsigned short h) {
    union { unsigned u; float f; } v; v.u = ((unsigned)h) << 16; return v.f;
}

// ---------------- pp_pre: emits bf16 hi/lo split of p1_in
__global__ __launch_bounds__(256) void k_pp_pre(
    const float* __restrict__ p1,
    const float* __restrict__ W0, const float* __restrict__ b0,
    const float* __restrict__ W1, const float* __restrict__ b1,
    unsigned short* __restrict__ p1h, unsigned short* __restrict__ p1l)
{
    int a = blockIdx.x * 256 + threadIdx.x;
    if (a >= N_ATOMS) return;
    const float4* src = reinterpret_cast<const float4*>(p1 + (size_t)a * N_PROP);
    float4 v0 = src[0], v1 = src[1], v2 = src[2], v3 = src[3];
    float x[N_PROP] = {v0.x,v0.y,v0.z,v0.w, v1.x,v1.y,v1.z,v1.w,
                       v2.x,v2.y,v2.z,v2.w, v3.x,v3.y,v3.z,v3.w};
    float h[W];
#pragma unroll
    for (int c = 0; c < W; ++c) h[c] = b0[c];
#pragma unroll
    for (int k = 0; k < N_PROP; ++k)
#pragma unroll
        for (int c = 0; c < W; ++c) h[c] += x[k] * W0[k*W + c];
#pragma unroll
    for (int c = 0; c < W; ++c) h[c] = fast_tanh(h[c]);
    float y[W];
#pragma unroll
    for (int c = 0; c < W; ++c) y[c] = b1[c];
#pragma unroll
    for (int k = 0; k < W; ++k)
#pragma unroll
        for (int c = 0; c < W; ++c) y[c] += h[k] * W1[k*W + c];
    union { unsigned short u[8]; s16x8 v; } hi0, hi1, lo0, lo1;
#pragma unroll
    for (int c = 0; c < W; ++c) {
        float t = fast_tanh(y[c]);
        unsigned short hb = bf16r(t);
        unsigned short lb = bf16r(t - bf16f(hb));
        if (c < 8) { hi0.u[c] = hb; lo0.u[c] = lb; }
        else       { hi1.u[c-8] = hb; lo1.u[c-8] = lb; }
    }
    s16x8* dh = reinterpret_cast<s16x8*>(p1h + (size_t)a * W);
    s16x8* dl = reinterpret_cast<s16x8*>(p1l + (size_t)a * W);
    dh[0] = hi0.v; dh[1] = hi1.v;
    dl[0] = lo0.v; dl[1] = lo1.v;
}

// C-layout (lane holds rows 4g+i of pair column r) -> B-layout (lane needs ch 8g+j), hi/lo
__device__ __forceinline__ void exch_to_B(float x0, float x1, float x2, float x3,
                                          int r, int g, bool augment,
                                          s16x8& Bh, s16x8& Bl)
{
    unsigned short h0 = bf16r(x0), h1 = bf16r(x1), h2 = bf16r(x2), h3 = bf16r(x3);
    unsigned hw0 = (unsigned)h0 | ((unsigned)h1 << 16);
    unsigned hw1 = (unsigned)h2 | ((unsigned)h3 << 16);
    unsigned short l0 = bf16r(x0 - bf16f(h0)), l1 = bf16r(x1 - bf16f(h1));
    unsigned short l2 = bf16r(x2 - bf16f(h2)), l3 = bf16r(x3 - bf16f(h3));
    unsigned lw0 = (unsigned)l0 | ((unsigned)l1 << 16);
    unsigned lw1 = (unsigned)l2 | ((unsigned)l3 << 16);
    int t0 = (r + 32*g) & 63, t1 = (r + 32*g + 16) & 63;
    unsigned bw0 = (unsigned)__shfl((int)hw0, t0);
    unsigned bw1 = (unsigned)__shfl((int)hw1, t0);
    unsigned bw2 = (unsigned)__shfl((int)hw0, t1);
    unsigned bw3 = (unsigned)__shfl((int)hw1, t1);
    unsigned cw0 = (unsigned)__shfl((int)lw0, t0);
    unsigned cw1 = (unsigned)__shfl((int)lw1, t0);
    unsigned cw2 = (unsigned)__shfl((int)lw0, t1);
    unsigned cw3 = (unsigned)__shfl((int)lw1, t1);
    if (g >= 2) {
        bw0 = (augment && g == 2) ? 0x3F80u : 0u;
        bw1 = bw2 = bw3 = 0u;
        cw0 = cw1 = cw2 = cw3 = 0u;
    }
    union { unsigned u[4]; s16x8 v; } ph, pl;
    ph.u[0] = bw0; ph.u[1] = bw1; ph.u[2] = bw2; ph.u[3] = bw3;
    pl.u[0] = cw0; pl.u[1] = cw1; pl.u[2] = cw2; pl.u[3] = cw3;
    Bh = ph.v; Bl = pl.v;
}

__device__ __forceinline__ s16x8 exch_hi(float x0, float x1, float x2, float x3,
                                         int r, int g)
{
    unsigned short h0 = bf16r(x0), h1 = bf16r(x1), h2 = bf16r(x2), h3 = bf16r(x3);
    unsigned hw0 = (unsigned)h0 | ((unsigned)h1 << 16);
    unsigned hw1 = (unsigned)h2 | ((unsigned)h3 << 16);
    int t0 = (r + 32*g) & 63, t1 = (r + 32*g + 16) & 63;
    unsigned bw0 = (unsigned)__shfl((int)hw0, t0);
    unsigned bw1 = (unsigned)__shfl((int)hw1, t0);
    unsigned bw2 = (unsigned)__shfl((int)hw0, t1);
    unsigned bw3 = (unsigned)__shfl((int)hw1, t1);
    if (g >= 2) { bw0 = bw1 = bw2 = bw3 = 0u; }
    union { unsigned u[4]; s16x8 v; } ph;
    ph.u[0] = bw0; ph.u[1] = bw1; ph.u[2] = bw2; ph.u[3] = bw3;
    return ph.v;
}

// ---------------- pair kernel
// pi1 packing: tile t (0..11), A-row r' -> ch = 4*(t&3)+(r'>>2), bp = 4*(t>>2)+(r'&3)
// lane (r,g) reg i: ch = 4*(t&3)+g (const per tile), bp = 4*(t>>2)+i -> in-register
// basis contraction, no cross-lane reduce.
template<int USE_RANK>
__global__ __launch_bounds__(256) void k_pair_mfma(
    const int*   __restrict__ ind2,
    const float* __restrict__ basis,
    const unsigned short* __restrict__ p1h,
    const unsigned short* __restrict__ p1l,
    const float* __restrict__ Wpi0, const float* __restrict__ bpi0,
    const float* __restrict__ Wpi1, const float* __restrict__ bpi1,
    const float* __restrict__ Wii0, const float* __restrict__ Wii1,
    float* __restrict__ i_pair_out,
    const unsigned* __restrict__ starts,
    const unsigned* __restrict__ rank,
    unsigned* __restrict__ cursor,
    float* __restrict__ svals)
{
    __shared__ s16x8 a2_lds[12][4][16];   // [t][g][r] 16B entries -> conflict-free ds_read_b128

    const int lane = threadIdx.x & 63;
    const int w    = threadIdx.x >> 6;
    const int r    = lane & 15;
    const int g    = lane >> 4;

    // fill a2 LDS (768 entries, 3 per thread)
    for (int e = threadIdx.x; e < 768; e += 256) {
        int t  = e >> 6;
        int rr = (e >> 2) & 15;   // A-row r'
        int gg = e & 3;
        int ch = 4*(t & 3) + (rr >> 2);
        int bp = 4*(t >> 2) + (rr & 3);
        s16x8 val;
#pragma unroll
        for (int j = 0; j < 8; ++j) {
            int k = 8*gg + j;
            float wv = 0.0f;
            if (bp < N_BASIS) {
                if (k < W)       wv = Wpi1[k*(W*N_BASIS) + ch*N_BASIS + bp];
                else if (k == W) wv = bpi1[ch*N_BASIS + bp];
            }
            val[j] = (short)bf16r(wv);
        }
        a2_lds[t][gg][rr] = val;
    }

    s16x8 a1, a3, a4;
#pragma unroll
    for (int j = 0; j < 8; ++j) {
        int k = 8*g + j;
        a1[j] = (short)bf16r(Wpi0[k*W + r]);
        a3[j] = (short)(k < W ? bf16r(Wii0[k*W + r]) : 0);
        a4[j] = (short)(k < W ? bf16r(Wii1[k*W + r]) : 0);
    }
    float b0v[4];
#pragma unroll
    for (int i = 0; i < 4; ++i) b0v[i] = bpi0[4*g + i];

    __syncthreads();

    for (int tile = blockIdx.x * 4 + w; tile < NT; tile += gridDim.x * 4) {
        const int p0 = tile * 16;
        const int p  = p0 + r;
        int2 ij = reinterpret_cast<const int2*>(ind2)[p];
        int atom = (g < 2) ? ij.x : ij.y;

        const s16x8 B1h = *reinterpret_cast<const s16x8*>(p1h + (size_t)atom * W + (g & 1) * 8);
        const s16x8 B1l = *reinterpret_cast<const s16x8*>(p1l + (size_t)atom * W + (g & 1) * 8);

        // full basis row (dup lanes across g merge in the coalescer); 8B-aligned float2 loads
        const float2* bb = reinterpret_cast<const float2*>(basis + (size_t)p * N_BASIS);
        float bas[12];
#pragma unroll
        for (int q = 0; q < 5; ++q) { float2 t2 = bb[q]; bas[2*q] = t2.x; bas[2*q+1] = t2.y; }
        bas[10] = 0.0f; bas[11] = 0.0f;

        // pi0 (K=32), hi/lo
        f32x4 acc = {0.f, 0.f, 0.f, 0.f};
        acc = __builtin_amdgcn_mfma_f32_16x16x32_bf16(a1, B1h, acc, 0, 0, 0);
        acc = __builtin_amdgcn_mfma_f32_16x16x32_bf16(a1, B1l, acc, 0, 0, 0);
        float h0v[4];
#pragma unroll
        for (int i = 0; i < 4; ++i) h0v[i] = fast_tanh(acc[i] + b0v[i]);

        s16x8 B2h, B2l;
        exch_to_B(h0v[0], h0v[1], h0v[2], h0v[3], r, g, true, B2h, B2l);

        // pi1: 12 tiles, in-register basis contraction
        float vloc[4] = {0.f, 0.f, 0.f, 0.f};
#pragma unroll
        for (int t = 0; t < 12; ++t) {
            s16x8 af = a2_lds[t][g][r];
            f32x4 z = {0.f, 0.f, 0.f, 0.f};
            z = __builtin_amdgcn_mfma_f32_16x16x32_bf16(af, B2h, z, 0, 0, 0);
            z = __builtin_amdgcn_mfma_f32_16x16x32_bf16(af, B2l, z, 0, 0, 0);
#pragma unroll
            for (int i = 0; i < 4; ++i)
                vloc[t & 3] += fast_tanh(z[i]) * bas[4*(t >> 2) + i];
        }
        // relayout: lane (r,g) holds channels {4m+g}; give every lane all 16
        float fm[16];
#pragma unroll
        for (int m = 0; m < 4; ++m)
#pragma unroll
            for (int q = 0; q < 4; ++q)
                fm[4*m + q] = __shfl(vloc[m], r + 16*q);   // fm[c] = channel c of pair r

        s16x8 B3h;
        if (g == 0) {
#pragma unroll
            for (int j = 0; j < 8; ++j) B3h[j] = (short)bf16r(fm[j]);
        } else if (g == 1) {
#pragma unroll
            for (int j = 0; j < 8; ++j) B3h[j] = (short)bf16r(fm[8 + j]);
        } else {
#pragma unroll
            for (int j = 0; j < 8; ++j) B3h[j] = 0;
        }

        // ii0
        f32x4 ua = {0.f, 0.f, 0.f, 0.f};
        ua = __builtin_amdgcn_mfma_f32_16x16x32_bf16(a3, B3h, ua, 0, 0, 0);
        s16x8 B4h = exch_hi(fast_tanh(ua[0]), fast_tanh(ua[1]),
                            fast_tanh(ua[2]), fast_tanh(ua[3]), r, g);

        // ii1
        f32x4 wa = {0.f, 0.f, 0.f, 0.f};
        wa = __builtin_amdgcn_mfma_f32_16x16x32_bf16(a4, B4h, wa, 0, 0, 0);
        float4 outv = make_float4(fast_tanh(wa[0]), fast_tanh(wa[1]),
                                  fast_tanh(wa[2]), fast_tanh(wa[3]));
        *reinterpret_cast<float4*>(i_pair_out + (size_t)p * W + 4*g) = outv;

        unsigned pos;
        if (USE_RANK) {
            pos = starts[ij.x] + rank[p];      // both L2-resident / coalesced
        } else {
            unsigned pp = 0;
            if (g == 0) pp = atomicAdd(&cursor[ij.x], 1u);
            pos = (unsigned)__shfl((int)pp, r);
        }
        *reinterpret_cast<float4*>(svals + (size_t)pos * W + 4*g) = outv;
    }
}

// ---------------- IP pipeline
__global__ __launch_bounds__(256) void k_count(const int* __restrict__ ind2,
                                               unsigned* __restrict__ counts,
                                               unsigned* __restrict__ rank)
{
    int p = blockIdx.x * 256 + threadIdx.x;
    if (p >= N_PAIRS) return;
    rank[p] = atomicAdd(&counts[ind2[2*p]], 1u);
}

// per-block exclusive scan (partial) + block total
__global__ __launch_bounds__(SCAN_BLK) void k_scanA(const unsigned* __restrict__ counts,
                                                    unsigned* __restrict__ starts,
                                                    unsigned* __restrict__ bsum)
{
    __shared__ unsigned sc[SCAN_BLK];
    int a = blockIdx.x * SCAN_BLK + threadIdx.x;
    unsigned c = (a < N_ATOMS) ? counts[a] : 0u;
    sc[threadIdx.x] = c;
    __syncthreads();
    for (int off = 1; off < SCAN_BLK; off <<= 1) {
        unsigned v = sc[threadIdx.x];
        unsigned add = (threadIdx.x >= off) ? sc[threadIdx.x - off] : 0u;
        __syncthreads();
        sc[threadIdx.x] = v + add;
        __syncthreads();
    }
    if (a < N_ATOMS) starts[a] = sc[threadIdx.x] - c;   // exclusive, pre-offset
    if (threadIdx.x == SCAN_BLK - 1) bsum[blockIdx.x] = sc[SCAN_BLK - 1];
}

__global__ void k_scanB(unsigned* __restrict__ bsum, unsigned* __restrict__ boff)
{
    if (threadIdx.x == 0) {
        unsigned run = 0;
        for (int b = 0; b < NB; ++b) { boff[b] = run; run += bsum[b]; }
    }
}

__global__ __launch_bounds__(SCAN_BLK) void k_scanC(unsigned* __restrict__ starts,
                                                    const unsigned* __restrict__ boff,
                                                    unsigned* __restrict__ cursor)
{
    int a = blockIdx.x * SCAN_BLK + threadIdx.x;
    if (a >= N_ATOMS) return;
    unsigned s = starts[a] + boff[blockIdx.x];
    starts[a] = s;
    cursor[a] = s;
}

// streaming reduce over sorted values
__global__ __launch_bounds__(256) void k_reduce_stream(const unsigned* __restrict__ starts,
                                                       const unsigned* __restrict__ counts,
                                                       const float* __restrict__ svals,
                                                       float* __restrict__ p_sum)
{
    int a = blockIdx.x * 4 + (threadIdx.x >> 6);
    if (a >= N_ATOMS) return;
    int lane = threadIdx.x & 63;
    int c = lane & 15, q = lane >> 4;
    unsigned n = counts[a], st = starts[a];
    float acc = 0.0f;
    for (unsigned k = q; k < n; k += 4)
        acc += svals[(size_t)(st + k) * W + c];
    acc += __shfl_xor(acc, 16);
    acc += __shfl_xor(acc, 32);
    if (q == 0) p_sum[(size_t)a * W + c] = acc;
}

// ---------------- pp_post
__global__ __launch_bounds__(256) void k_pp_post(
    const float* __restrict__ p_sum,
    const float* __restrict__ W0, const float* __restrict__ W1,
    float* __restrict__ p1_new)
{
    int a = blockIdx.x * 256 + threadIdx.x;
    if (a >= N_ATOMS) return;
    const float4* src = reinterpret_cast<const float4*>(p_sum + (size_t)a * W);
    float4 v0 = src[0], v1 = src[1], v2 = src[2], v3 = src[3];
    float x[W] = {v0.x,v0.y,v0.z,v0.w, v1.x,v1.y,v1.z,v1.w,
                  v2.x,v2.y,v2.z,v2.w, v3.x,v3.y,v3.z,v3.w};
    float h[W];
#pragma unroll
    for (int c = 0; c < W; ++c) h[c] = 0.0f;
#pragma unroll
    for (int k = 0; k < W; ++k)
#pragma unroll
        for (int c = 0; c < W; ++c) h[c] += x[k] * W0[k*W + c];
#pragma unroll
    for (int c = 0; c < W; ++c) h[c] = fast_tanh(h[c]);
    float y[W];
#pragma unroll
    for (int c = 0; c < W; ++c) y[c] = 0.0f;
#pragma unroll
    for (int k = 0; k < W; ++k)
#pragma unroll
        for (int c = 0; c < W; ++c) y[c] += h[k] * W1[k*W + c];
    float4* dst = reinterpret_cast<float4*>(p1_new + (size_t)a * W);
    dst[0] = make_float4(fast_tanh(y[0]),  fast_tanh(y[1]),  fast_tanh(y[2]),  fast_tanh(y[3]));
    dst[1] = make_float4(fast_tanh(y[4]),  fast_tanh(y[5]),  fast_tanh(y[6]),  fast_tanh(y[7]));
    dst[2] = make_float4(fast_tanh(y[8]),  fast_tanh(y[9]),  fast_tanh(y[10]), fast_tanh(y[11]));
    dst[3] = make_float4(fast_tanh(y[12]), fast_tanh(y[13]), fast_tanh(y[14]), fast_tanh(y[15]));
}

extern "C" void kernel_launch(void* const* d_in, const int* in_sizes, int n_in,
                              void* d_out, int out_size, void* d_ws, size_t ws_size,
                              hipStream_t stream) {
    const int*   ind2   = (const int*)d_in[0];
    const float* p1     = (const float*)d_in[1];
    const float* basis  = (const float*)d_in[2];
    const float* Wpre0  = (const float*)d_in[3];
    const float* bpre0  = (const float*)d_in[4];
    const float* Wpre1  = (const float*)d_in[5];
    const float* bpre1  = (const float*)d_in[6];
    const float* Wpi0   = (const float*)d_in[7];
    const float* bpi0   = (const float*)d_in[8];
    const float* Wpi1   = (const float*)d_in[9];
    const float* bpi1   = (const float*)d_in[10];
    const float* Wii0   = (const float*)d_in[11];
    const float* Wii1   = (const float*)d_in[12];
    const float* Wpost0 = (const float*)d_in[13];
    const float* Wpost1 = (const float*)d_in[14];

    float* out    = (float*)d_out;
    float* p1_new = out;                          // (N_ATOMS, W)
    float* i_pair = out + (size_t)N_ATOMS * W;    // (N_PAIRS, W)

    char* ws = (char*)d_ws;
    unsigned short* p1h = (unsigned short*)ws;                    ws += (size_t)N_ATOMS * W * 2;
    unsigned short* p1l = (unsigned short*)ws;                    ws += (size_t)N_ATOMS * W * 2;
    float*    p_sum  = (float*)ws;                                ws += (size_t)N_ATOMS * W * 4;
    unsigned* counts = (unsigned*)ws;                             ws += (size_t)N_ATOMS * 4;
    unsigned* starts = (unsigned*)ws;                             ws += (size_t)N_ATOMS * 4;
    unsigned* cursor = (unsigned*)ws;                             ws += (size_t)N_ATOMS * 4;
    unsigned* bsum   = (unsigned*)ws;                             ws += 1024 * 4;
    unsigned* boff   = (unsigned*)ws;                             ws += 1024 * 4;
    float*    svals  = (float*)ws;                                ws += (size_t)N_PAIRS * W * 4;
    unsigned* rank   = (unsigned*)ws;                             ws += (size_t)N_PAIRS * 4;

    int use_rank = (ws_size >= (size_t)(ws - (char*)d_ws));

    hipMemsetAsync(counts, 0, (size_t)N_ATOMS * sizeof(unsigned), stream);
    k_pp_pre<<<(N_ATOMS + 255) / 256, 256, 0, stream>>>(p1, Wpre0, bpre0, Wpre1, bpre1, p1h, p1l);
    k_count<<<(N_PAIRS + 255) / 256, 256, 0, stream>>>(ind2, counts, use_rank ? rank : cursor);
    k_scanA<<<NB, SCAN_BLK, 0, stream>>>(counts, starts, bsum);
    k_scanB<<<1, 64, 0, stream>>>(bsum, boff);
    k_scanC<<<NB, SCAN_BLK, 0, stream>>>(starts, boff, cursor);

    if (use_rank) {
        k_pair_mfma<1><<<2560, 256, 0, stream>>>(ind2, basis, p1h, p1l,
                                                 Wpi0, bpi0, Wpi1, bpi1, Wii0, Wii1,
                                                 i_pair, starts, rank, cursor, svals);
    } else {
        k_pair_mfma<0><<<2560, 256, 0, stream>>>(ind2, basis, p1h, p1l,
                                                 Wpi0, bpi0, Wpi1, bpi1, Wii0, Wii1,
                                                 i_pair, starts, rank, cursor, svals);
    }
    k_reduce_stream<<<(N_ATOMS + 3) / 4, 256, 0, stream>>>(starts, counts, svals, p_sum);
    k_pp_post<<<(N_ATOMS + 255) / 256, 256, 0, stream>>>(p_sum, Wpost0, Wpost1, p1_new);
}